// Round 3
// baseline (232.802 us; speedup 1.0000x reference)
//
#include <hip/hip_runtime.h>

// LSTM B=8192,T=256,I=1,H=50 via MFMA -- R19: TWO-GROUP INTRA-BLOCK PIPELINE.
// R16 (161us) counters decompose the 1512-cyc step wall EXACTLY into three
// serialized phases: VALU 59% (26 chains x 146cyc /4 SIMD = 950), LDS-read
// 27% (52 b128 x 8 = 416), MFMA 14% (208) -- lockstep waves, zero overlap.
// R17 (fewer reads, fewer waves) neutral; R18 (block skew) neutral -- in-phase
// is a stable attractor across blocks (laggard sees less contention, catches
// up). Fix: bring the anti-phase INSIDE one barrier domain where program
// order enforces it. Block = 32 batches, TWO independent 16-batch groups
// (A,B) pipelined a half-step apart, 1 block/CU (NBLK=256):
//   half-step: issue grp-X frag ds_reads -> full act chain of grp-Y (~146cyc
//   VALU, independent of the reads) -> MFMA-X -> store hY -> barrier.
// LDS phase and MFMA hide under the other group's trans by construction.
// Per step: 2 halves x (475 VALU/SIMD + sync) ~= 1100 cyc (vs 1512).
//
// Math per chain (R16, rcp-fused, 7 quarter-rate ops, bit-identical):
//   c2' = [c2*D2 + 2L*(Eg-1)*D1] * rcp(D1*D2),  D1=1+Ef, D2=(Eg+1)(1+Ei)
//   h   = (Ec-1) * rcp((Ec+1)(1+Eo)),           Ec=exp2(clamp(c2'))
// Structure: wave wv(0..12) owns row-tile T=wv for BOTH groups; wave 13 =
// x-wave (handles k=50 x-column of both groups). 4 LDS planes A0/A1/B0/B1
// (double-buffer per group); each barrier separates one group's stores from
// that group's next reads. W fragments shared across groups (same weights).
// Pad lanes (unit>=50) redirect to slots 54/55 per plane. VGPR ~32.

#define NTH 896          // 14 waves
#define TST 256
#define MBG 16           // batches per group (MFMA N=16)
#define NBLK 256         // 8192 / 32
#define HR 72            // h row stride in halfs (16B-aligned b128 frag reads)
#define HSZ (MBG * HR)   // 1152 halfs per plane

#define A0O 0
#define A1O HSZ
#define B0O (2 * HSZ)
#define B1O (3 * HSZ)

#define LOG2E 1.44269504088896f

typedef __attribute__((ext_vector_type(8))) _Float16 half8;
typedef __attribute__((ext_vector_type(4))) float float4v;

__device__ __forceinline__ float rcp_(float v)  { return __builtin_amdgcn_rcpf(v); }
__device__ __forceinline__ float exp2_(float v) { return __builtin_amdgcn_exp2f(v); }
__device__ __forceinline__ unsigned short f16bits(float v) {
    _Float16 h = (_Float16)v;                 // RNE
    return *(unsigned short*)&h;
}

__global__ __launch_bounds__(NTH, 4) void lstm_mfma(
    const float* __restrict__ x,      // [8192][256]
    const float* __restrict__ W_ih,   // [200]
    const float* __restrict__ W_hh,   // [200][50]
    const float* __restrict__ b_ih,   // [200]
    const float* __restrict__ b_hh,   // [200]
    const float* __restrict__ W_lin,  // [50]
    const float* __restrict__ b_lin,  // [1]
    float* __restrict__ out)          // [8192]
{
    __shared__ __align__(16) unsigned short Hh[4 * HSZ];   // 4 fp16 h planes

    const int tid  = threadIdx.x;
    const int wv   = tid >> 6;      // 0..12 = tile T; 13 = x-wave
    const int ln   = tid & 63;
    const int lrow = ln & 15;       // batch-in-group / A-row m / D col
    const int quad = ln >> 4;
    const int bbase = (int)blockIdx.x * (2 * MBG);
    const int T = wv;

    // ---- W-operand fragments (shared by both groups; one-time L2 reads).
    // Row gr=T*16+lrow -> unit j=gr>>2, gate g=gr&3, W row = g*50+j.
    // k = q2*32 + quad*8 + i; k=50 -> W_ih, k=51 -> bias; pad rows (j>=50)
    // zero (incl. wave 13 -- it never issues MFMA).
    // Pre-scale: sigmoid rows (g!=2) by -log2e, g rows by +2log2e.
    half8 wh[2];
    {
        const int gr = T * 16 + lrow;
        const int j  = gr >> 2, g = gr & 3;
        const int row = g * 50 + j;             // only dereferenced when j<50
        const float scl = (g == 2) ? (2.0f * LOG2E) : (-LOG2E);
        #pragma unroll
        for (int q2 = 0; q2 < 2; ++q2) {
            half8 h8;
            #pragma unroll
            for (int i = 0; i < 8; ++i) {
                const int k = q2 * 32 + quad * 8 + i;
                float V = 0.0f;
                if (j < 50) {
                    if (k < 50)       V = W_hh[row * 50 + k];
                    else if (k == 50) V = W_ih[row];
                    else if (k == 51) V = b_ih[row] + b_hh[row];
                }
                h8[i] = (_Float16)(V * scl);    // single fp16 product (RNE)
            }
            wh[q2] = h8;
        }
    }

    // ---- init: zero all 4 planes; x(0) into A0/B0 k=50; bias 1.0 k=51 all.
    for (int i = tid; i < 2 * HSZ; i += NTH)   // 4*HSZ halfs = 2*HSZ uints
        ((unsigned int*)Hh)[i] = 0u;
    __syncthreads();
    if (tid < 2 * MBG) {
        const int g = tid >> 4, r = tid & 15;
        const float xv = x[(bbase + tid) * TST + 0];
        Hh[(g ? B0O : A0O) + r * HR + 50] = f16bits(xv);
    }
    if (tid < MBG) {
        #pragma unroll
        for (int p = 0; p < 4; ++p)
            Hh[p * HSZ + tid * HR + 51] = 0x3C00;   // fp16(1.0), never rewritten
    }
    __syncthreads();

    float c2A = 0.0f, c2B = 0.0f;              // c in the x2log2e domain
    const unsigned short* HrP = &Hh[lrow * HR + quad * 8];  // frag read base
    int jw = T * 4 + quad;                                  // unit this lane writes
    if (jw >= 50) jw = 52 + quad;                           // pad redirect (54/55)
    unsigned short* Hw = &Hh[lrow * HR + jw];               // write base (per-plane off)
    const float* xrA = &x[(bbase + lrow) * TST];            // x-wave rows
    const float* xrB = &x[(bbase + MBG + lrow) * TST];
    const float4v z4 = {0.f, 0.f, 0.f, 0.f};                // zero C operand

    // activation chain: gates (ai,af,ag,ao) pre-scaled i/f/o by -L, g by +2L
    auto act = [&](const float4v a4, float& c2) -> unsigned short {
        const float Ei = exp2_(a4[0]);
        const float Ef = exp2_(a4[1]);
        const float Eg = exp2_(a4[2]);
        const float Eo = exp2_(a4[3]);
        const float D1 = 1.0f + Ef;
        const float D2 = (Eg + 1.0f) * (1.0f + Ei);
        const float R  = rcp_(D1 * D2);
        const float tg = (Eg - 1.0f) * D1;
        const float nm = fmaf(2.0f * LOG2E, tg, c2 * D2);
        c2 = fminf(nm * R, 120.0f);            // clamp: exp2 overflow guard
        const float Ec = exp2_(c2);
        const float R2 = rcp_((Ec + 1.0f) * (1.0f + Eo));
        return f16bits((Ec - 1.0f) * R2);
    };

    // one half-step: issue frag reads of one group (roff), run the OTHER
    // group's act chain (gIn -> h, stored to woff), then MFMA the reads
    // into gOut. Program order puts ~146 cyc of independent VALU between
    // ds_read issue and MFMA use -> LDS latency+pipe hidden by construction.
    auto hstep = [&](int roff, int woff, float4v& gIn, float& c2, float4v& gOut) {
        const half8 b0 = *(const half8*)(HrP + roff);
        const half8 b1 = *(const half8*)(HrP + roff + 32);
        const unsigned short hb = act(gIn, c2);
        float4v a4 = __builtin_amdgcn_mfma_f32_16x16x32_f16(wh[0], b0, z4, 0, 0, 0);
        a4 = __builtin_amdgcn_mfma_f32_16x16x32_f16(wh[1], b1, a4, 0, 0, 0);
        gOut = a4;
        Hw[woff] = hb;                         // unconditional (pad-redirected)
    };

    // ---- prologue: gatesA(0) from A0 (compute waves only)
    float4v gA = z4, gB = z4;
    if (wv != 13) {
        const half8 b0 = *(const half8*)(HrP + A0O);
        const half8 b1 = *(const half8*)(HrP + A0O + 32);
        gA = __builtin_amdgcn_mfma_f32_16x16x32_f16(wh[0], b0, z4, 0, 0, 0);
        gA = __builtin_amdgcn_mfma_f32_16x16x32_f16(wh[1], b1, gA, 0, 0, 0);
    }

    // ---- main loop: each body advances both groups 2 steps (4 half-steps).
    // Invariant at top: gA = gates_A(t); B0 = {h_B(t), x_B(t)}; A planes
    // hold h_A(t) in A0 (consumed by the prologue/previous half already).
    #pragma unroll 1
    for (int t2 = 0; t2 < TST / 2; ++t2) {
        if (wv == 13) {
            // x-wave: all 4 loads at iteration top (latency hidden); each
            // store lands in the plane the next half-step's MFMA will read,
            // before the barrier that publishes it.
            const float xa1 = xrA[2 * t2 + 1];
            const float xb1 = xrB[2 * t2 + 1];
            const float xa2 = xrA[(2 * t2 + 2) & 255];   // t2=127: junk, never used
            const float xb2 = xrB[(2 * t2 + 2) & 255];
            if (ln < 16) Hh[A1O + lrow * HR + 50] = f16bits(xa1);
            __syncthreads();                   // b1: A1 (h_A(t+1), x_A(t+1)) ready
            if (ln < 16) Hh[B1O + lrow * HR + 50] = f16bits(xb1);
            __syncthreads();                   // b2: B1 ready
            if (ln < 16) Hh[A0O + lrow * HR + 50] = f16bits(xa2);
            __syncthreads();                   // b3: A0 (t+2) ready
            if (ln < 16) Hh[B0O + lrow * HR + 50] = f16bits(xb2);
            __syncthreads();                   // b4: B0 (t+2) ready
        } else {
            hstep(B0O, A1O, gA, c2A, gB);      // read B(t) | trans A(t)->h_A(t+1)
            __syncthreads();
            hstep(A1O, B1O, gB, c2B, gA);      // read A(t+1) | trans B(t)->h_B(t+1)
            __syncthreads();
            hstep(B1O, A0O, gA, c2A, gB);      // read B(t+1) | trans A(t+1)->h_A(t+2)
            __syncthreads();
            hstep(A0O, B0O, gB, c2B, gA);      // read A(t+2) | trans B(t+1)->h_B(t+2)
            __syncthreads();
        }
    }

    // ---- epilogue: final h_A(256) in A0, h_B(256) in B0 (k=50/51 slots are
    // junk/bias but only k<50 is read).
    if (tid < 2 * MBG) {
        const int g = tid >> 4, r = tid & 15;
        const unsigned short* hp = &Hh[(g ? B0O : A0O) + r * HR];
        float s = b_lin[0];
        #pragma unroll 10
        for (int k = 0; k < 50; ++k) {
            float hk = (float)(*(const _Float16*)&hp[k]);
            s += hk * W_lin[k];
        }
        out[bbase + tid] = s;
    }
}

extern "C" void kernel_launch(void* const* d_in, const int* in_sizes, int n_in,
                              void* d_out, int out_size, void* d_ws, size_t ws_size,
                              hipStream_t stream) {
    const float* x     = (const float*)d_in[0];
    const float* W_ih  = (const float*)d_in[1];
    const float* W_hh  = (const float*)d_in[2];
    const float* b_ih  = (const float*)d_in[3];
    const float* b_hh  = (const float*)d_in[4];
    const float* W_lin = (const float*)d_in[5];
    const float* b_lin = (const float*)d_in[6];
    float* out = (float*)d_out;

    lstm_mfma<<<dim3(NBLK), dim3(NTH), 0, stream>>>(
        x, W_ih, W_hh, b_ih, b_hh, W_lin, b_lin, out);
}